// Round 1
// baseline (112.595 us; speedup 1.0000x reference)
//
#include <hip/hip_runtime.h>
#include <hip/hip_bf16.h>

#define F_IN 128
#define F_OUT 64

// ---------------------------------------------------------------------------
// Kernel 1: pre_sup = x @ W   (fp32, K=128, N=64)
// Block = 256 threads (4 waves), 16 rows/block.
// wave == row-quad group: rq = tid>>6 handles rows rq*4..rq*4+3, col = tid&63.
// W staged [k][col] in LDS (32 KB, lane-stride-1 -> 2-way bank alias = free),
// x rows staged in LDS (8 KB); x reads are wave-uniform broadcasts (free).
// ---------------------------------------------------------------------------
__global__ __launch_bounds__(256) void gcn_gemm(
    const float* __restrict__ x, const float* __restrict__ w,
    float* __restrict__ pre, int n_nodes) {
  __shared__ __align__(16) float ws[F_IN * F_OUT];   // 32 KB
  __shared__ __align__(16) float xs[16][F_IN];       // 8 KB
  const int tid = threadIdx.x;
  const int row0 = blockIdx.x * 16;

  // Load W: 8192 floats as 2048 float4 across 256 threads
  const float4* w4 = (const float4*)w;
  float4* ws4 = (float4*)ws;
#pragma unroll
  for (int i = 0; i < (F_IN * F_OUT / 4) / 256; ++i)
    ws4[tid + i * 256] = w4[tid + i * 256];

  // Load x tile: up to 16 rows x 128 floats = 512 float4
  const int nrows = min(16, n_nodes - row0);
  const float4* x4 = (const float4*)(x + (size_t)row0 * F_IN);
  float4* xs4 = (float4*)xs;
  for (int i = tid; i < nrows * (F_IN / 4); i += 256)
    xs4[i] = x4[i];
  __syncthreads();

  const int col = tid & 63;
  const int rq = tid >> 6;  // == wave id; all lanes of a wave share rq
  float acc[4] = {0.f, 0.f, 0.f, 0.f};

#pragma unroll 8
  for (int k = 0; k < F_IN; k += 4) {
    const float w0 = ws[(k + 0) * F_OUT + col];
    const float w1 = ws[(k + 1) * F_OUT + col];
    const float w2 = ws[(k + 2) * F_OUT + col];
    const float w3 = ws[(k + 3) * F_OUT + col];
#pragma unroll
    for (int r = 0; r < 4; ++r) {
      float4 xv = *(const float4*)&xs[rq * 4 + r][k];  // broadcast read
      acc[r] = fmaf(xv.x, w0, acc[r]);
      acc[r] = fmaf(xv.y, w1, acc[r]);
      acc[r] = fmaf(xv.z, w2, acc[r]);
      acc[r] = fmaf(xv.w, w3, acc[r]);
    }
  }

#pragma unroll
  for (int r = 0; r < 4; ++r) {
    const int row = row0 + rq * 4 + r;
    if (row < n_nodes) pre[(size_t)row * F_OUT + col] = acc[r];
  }
}

// ---------------------------------------------------------------------------
// Kernel 2: row_ptr[r] = lower_bound(edge_row, r), r in [0, n_nodes]
// edge_row is sorted; 3.2 MB -> L2-resident after first probes.
// ---------------------------------------------------------------------------
__global__ __launch_bounds__(256) void gcn_rowptr(
    const int* __restrict__ edge_row, int* __restrict__ row_ptr,
    int n_nodes, int n_edges) {
  const int r = blockIdx.x * blockDim.x + threadIdx.x;
  if (r > n_nodes) return;
  int lo = 0, hi = n_edges;
  while (lo < hi) {
    const int mid = (lo + hi) >> 1;
    if (edge_row[mid] < r) lo = mid + 1; else hi = mid;
  }
  row_ptr[r] = lo;
}

// ---------------------------------------------------------------------------
// Kernel 3: out[r][f] = relu( sum_{e in row r} val[e] * pre[col[e]][f] )
// One wave per row, lane = feature (F_OUT == 64 == wavefront).
// edge_col/edge_val loads are wave-uniform (HW broadcast); pre gather is a
// coalesced 256B load per edge. Sequential fp32 accumulation -> deterministic.
// ---------------------------------------------------------------------------
__global__ __launch_bounds__(256) void gcn_spmm(
    const float* __restrict__ pre, const int* __restrict__ row_ptr,
    const int* __restrict__ edge_col, const float* __restrict__ edge_val,
    float* __restrict__ out, int n_nodes) {
  const int lane = threadIdx.x & 63;
  const int row = (blockIdx.x * blockDim.x + threadIdx.x) >> 6;
  if (row >= n_nodes) return;
  const int e0 = row_ptr[row];
  const int e1 = row_ptr[row + 1];
  float acc = 0.f;
  for (int e = e0; e < e1; ++e) {
    const int c = edge_col[e];
    const float v = edge_val[e];
    acc = fmaf(v, pre[(size_t)c * F_OUT + lane], acc);
  }
  out[(size_t)row * F_OUT + lane] = fmaxf(acc, 0.f);
}

extern "C" void kernel_launch(void* const* d_in, const int* in_sizes, int n_in,
                              void* d_out, int out_size, void* d_ws, size_t ws_size,
                              hipStream_t stream) {
  const float* x        = (const float*)d_in[0];
  const float* w        = (const float*)d_in[1];
  const int*   edge_row = (const int*)d_in[2];
  const int*   edge_col = (const int*)d_in[3];
  const float* edge_val = (const float*)d_in[4];
  float* out = (float*)d_out;

  const int n_nodes = in_sizes[0] / F_IN;   // 50000
  const int n_edges = in_sizes[2];          // 800000

  float* pre    = (float*)d_ws;                                   // n_nodes*64 fp32
  int* row_ptr  = (int*)((char*)d_ws +
                         (size_t)n_nodes * F_OUT * sizeof(float)); // n_nodes+1 ints

  const int gemm_blocks = (n_nodes + 15) / 16;
  gcn_gemm<<<gemm_blocks, 256, 0, stream>>>(x, w, pre, n_nodes);

  const int rp_blocks = (n_nodes + 1 + 255) / 256;
  gcn_rowptr<<<rp_blocks, 256, 0, stream>>>(edge_row, row_ptr, n_nodes, n_edges);

  const int spmm_blocks = ((size_t)n_nodes * 64 + 255) / 256;
  gcn_spmm<<<spmm_blocks, 256, 0, stream>>>(pre, row_ptr, edge_col, edge_val,
                                            out, n_nodes);
}

// Round 2
// 97.756 us; speedup vs baseline: 1.1518x; 1.1518x over previous
//
#include <hip/hip_runtime.h>
#include <hip/hip_bf16.h>

#define F_IN 128
#define F_OUT 64

// ---------------------------------------------------------------------------
// Kernel 1: pre_sup = x @ W   (fp32, K=128, N=64) — no LDS.
// col = lane (64 cols == 64 lanes). 8 rows per wave, 4 waves/block = 32 rows.
// W rows are coalesced 256B loads (32 KB total -> L1/L2 resident, amortized
// over 8 rows). x reads are wave-uniform float4 broadcasts (1 txn each).
// VALU floor = 819 MFLOP / 157 TF ~ 5.2 us.
// ---------------------------------------------------------------------------
__global__ __launch_bounds__(256) void gcn_gemm(
    const float* __restrict__ x, const float* __restrict__ w,
    float* __restrict__ pre, int n_nodes) {
  const int lane = threadIdx.x & 63;
  const int wv   = threadIdx.x >> 6;
  const int row0 = blockIdx.x * 32 + wv * 8;
  if (row0 >= n_nodes) return;

  float acc[8] = {0.f, 0.f, 0.f, 0.f, 0.f, 0.f, 0.f, 0.f};
  const float* xr = x + (size_t)row0 * F_IN;

  if (row0 + 8 <= n_nodes) {  // fast path: full 8-row wave
#pragma unroll 2
    for (int k = 0; k < F_IN; k += 4) {
      const float w0 = w[(k + 0) * F_OUT + lane];
      const float w1 = w[(k + 1) * F_OUT + lane];
      const float w2 = w[(k + 2) * F_OUT + lane];
      const float w3 = w[(k + 3) * F_OUT + lane];
#pragma unroll
      for (int r = 0; r < 8; ++r) {
        const float4 xv = *(const float4*)(xr + (size_t)r * F_IN + k);  // uniform
        acc[r] = fmaf(xv.x, w0, acc[r]);
        acc[r] = fmaf(xv.y, w1, acc[r]);
        acc[r] = fmaf(xv.z, w2, acc[r]);
        acc[r] = fmaf(xv.w, w3, acc[r]);
      }
    }
#pragma unroll
    for (int r = 0; r < 8; ++r)
      pre[(size_t)(row0 + r) * F_OUT + lane] = acc[r];
  } else {  // tail: per-row guard
    const int nr = n_nodes - row0;
    for (int k = 0; k < F_IN; k += 4) {
      const float w0 = w[(k + 0) * F_OUT + lane];
      const float w1 = w[(k + 1) * F_OUT + lane];
      const float w2 = w[(k + 2) * F_OUT + lane];
      const float w3 = w[(k + 3) * F_OUT + lane];
      for (int r = 0; r < nr; ++r) {
        const float4 xv = *(const float4*)(xr + (size_t)r * F_IN + k);
        acc[r] = fmaf(xv.x, w0, acc[r]);
        acc[r] = fmaf(xv.y, w1, acc[r]);
        acc[r] = fmaf(xv.z, w2, acc[r]);
        acc[r] = fmaf(xv.w, w3, acc[r]);
      }
    }
    for (int r = 0; r < nr; ++r)
      pre[(size_t)(row0 + r) * F_OUT + lane] = acc[r];
  }
}

// ---------------------------------------------------------------------------
// Kernel 2: row_ptr[r] = lower_bound(edge_row, r)  (edge_row sorted)
// ---------------------------------------------------------------------------
__global__ __launch_bounds__(256) void gcn_rowptr(
    const int* __restrict__ edge_row, int* __restrict__ row_ptr,
    int n_nodes, int n_edges) {
  const int r = blockIdx.x * blockDim.x + threadIdx.x;
  if (r > n_nodes) return;
  int lo = 0, hi = n_edges;
  while (lo < hi) {
    const int mid = (lo + hi) >> 1;
    if (edge_row[mid] < r) lo = mid + 1; else hi = mid;
  }
  row_ptr[r] = lo;
}

// ---------------------------------------------------------------------------
// Kernel 3: out[r][f] = relu( sum_e val[e] * pre[col[e]][f] )
// One wave per row, lane = feature. Edge metadata loaded COALESCED (lane l
// takes edge e0+l), broadcast via __shfl; gathers unrolled 8-wide with 2
// accumulators so 8 independent 256B loads are in flight per vmcnt wait.
// Inactive slots contribute v=0 * pre[0][lane] (harmless, L1-hit).
// ---------------------------------------------------------------------------
__global__ __launch_bounds__(256) void gcn_spmm(
    const float* __restrict__ pre, const int* __restrict__ row_ptr,
    const int* __restrict__ edge_col, const float* __restrict__ edge_val,
    float* __restrict__ out, int n_nodes) {
  const int lane = threadIdx.x & 63;
  const int row = (blockIdx.x * blockDim.x + threadIdx.x) >> 6;
  if (row >= n_nodes) return;
  const int e0 = row_ptr[row];
  const int e1 = row_ptr[row + 1];
  float acc0 = 0.f, acc1 = 0.f;

  for (int base = e0; base < e1; base += 64) {
    const int cnt = min(64, e1 - base);
    int   myc = 0;
    float myv = 0.f;
    if (lane < cnt) {
      myc = edge_col[base + lane] << 6;  // pre-scaled to float offset of row
      myv = edge_val[base + lane];
    }
    const int nb = (cnt + 7) >> 3;  // batches of 8
    for (int b = 0; b < nb; ++b) {
      const int j0 = b * 8;
#pragma unroll
      for (int jj = 0; jj < 8; jj += 2) {
        const int   c0 = __shfl(myc, j0 + jj);
        const float v0 = __shfl(myv, j0 + jj);
        const int   c1 = __shfl(myc, j0 + jj + 1);
        const float v1 = __shfl(myv, j0 + jj + 1);
        acc0 = fmaf(v0, pre[c0 + lane], acc0);
        acc1 = fmaf(v1, pre[c1 + lane], acc1);
      }
    }
  }
  out[(size_t)row * F_OUT + lane] = fmaxf(acc0 + acc1, 0.f);
}

extern "C" void kernel_launch(void* const* d_in, const int* in_sizes, int n_in,
                              void* d_out, int out_size, void* d_ws, size_t ws_size,
                              hipStream_t stream) {
  const float* x        = (const float*)d_in[0];
  const float* w        = (const float*)d_in[1];
  const int*   edge_row = (const int*)d_in[2];
  const int*   edge_col = (const int*)d_in[3];
  const float* edge_val = (const float*)d_in[4];
  float* out = (float*)d_out;

  const int n_nodes = in_sizes[0] / F_IN;   // 50000
  const int n_edges = in_sizes[2];          // 800000

  float* pre   = (float*)d_ws;                                     // n_nodes*64 f32
  int* row_ptr = (int*)((char*)d_ws +
                        (size_t)n_nodes * F_OUT * sizeof(float));  // n_nodes+1 ints

  const int gemm_blocks = (n_nodes + 31) / 32;
  gcn_gemm<<<gemm_blocks, 256, 0, stream>>>(x, w, pre, n_nodes);

  const int rp_blocks = (n_nodes + 1 + 255) / 256;
  gcn_rowptr<<<rp_blocks, 256, 0, stream>>>(edge_row, row_ptr, n_nodes, n_edges);

  const int spmm_blocks = ((size_t)n_nodes * 64 + 255) / 256;
  gcn_spmm<<<spmm_blocks, 256, 0, stream>>>(pre, row_ptr, edge_col, edge_val,
                                            out, n_nodes);
}

// Round 3
// 50.582 us; speedup vs baseline: 2.2260x; 1.9326x over previous
//
#include <hip/hip_runtime.h>
#include <hip/hip_bf16.h>

#define F_IN 128
#define F_OUT 64

typedef __attribute__((ext_vector_type(8))) short short8;
typedef __attribute__((ext_vector_type(4))) float f32x4;

__device__ __forceinline__ unsigned short f2bf_rne(float f) {
  unsigned int u = __builtin_bit_cast(unsigned int, f);
  u += 0x7fffu + ((u >> 16) & 1u);
  return (unsigned short)(u >> 16);
}
__device__ __forceinline__ float bfu2f(unsigned short u) {
  return __builtin_bit_cast(float, (unsigned int)u << 16);
}

// ---------------------------------------------------------------------------
// Kernel 1: pre = bf16( x @ W )  via MFMA, fp32-class accuracy (hi/lo split).
// Block = 256 thr = 4 waves; wave -> one 16-row m-tile, all 64 cols.
// W^T staged in LDS as bf16 hi/lo, XOR-swizzled (^(n&7)<<4): conflict-free
// ds_write_b128 on stage and floor-rate ds_read_b128 on fragment loads.
// A-frags: 2 coalesced float4 per lane per k-step, converted on the fly.
// acc = ah*bh + al*bh + ah*bl  (error ~2^-17 relative).
// ---------------------------------------------------------------------------
__global__ __launch_bounds__(256) void gcn_gemm(
    const float* __restrict__ x, const float* __restrict__ w,
    unsigned short* __restrict__ pre, int n_nodes) {
  __shared__ __align__(16) unsigned short wt_hi[64 * 128];
  __shared__ __align__(16) unsigned short wt_lo[64 * 128];

  const int tid = threadIdx.x;
  // ---- stage W^T (n-major, k contiguous) ----
  {
    const int n = tid >> 2;            // 0..63
    const int kc = (tid & 3) << 5;     // 0,32,64,96
#pragma unroll
    for (int g = 0; g < 4; ++g) {
      short8 hv, lv;
#pragma unroll
      for (int i = 0; i < 8; ++i) {
        const float f = w[(kc + g * 8 + i) * F_OUT + n];
        const unsigned short h = f2bf_rne(f);
        const float hf = bfu2f(h);
        hv[i] = (short)h;
        lv[i] = (short)f2bf_rne(f - hf);
      }
      int off = (n << 8) + ((kc + g * 8) << 1);
      off ^= (n & 7) << 4;
      *(short8*)((char*)wt_hi + off) = hv;
      *(short8*)((char*)wt_lo + off) = lv;
    }
  }
  __syncthreads();

  const int lane = tid & 63;
  const int mt = blockIdx.x * 4 + (tid >> 6);
  const int m0 = mt * 16;
  if (m0 >= n_nodes) return;

  const int lrow = lane & 15;   // A row / B col / C col within tile
  const int lk = lane >> 4;     // k-group 0..3
  const bool full = (m0 + 16 <= n_nodes);
  const int arow = full ? (m0 + lrow) : min(m0 + lrow, n_nodes - 1);

  f32x4 acc[4];
#pragma unroll
  for (int i = 0; i < 4; ++i) acc[i] = (f32x4){0.f, 0.f, 0.f, 0.f};

#pragma unroll
  for (int ks = 0; ks < 4; ++ks) {
    const float4* xp =
        (const float4*)(x + (size_t)arow * F_IN + ks * 32 + lk * 8);
    const float4 q0 = xp[0];
    const float4 q1 = xp[1];
    const float fv[8] = {q0.x, q0.y, q0.z, q0.w, q1.x, q1.y, q1.z, q1.w};
    short8 ah, al;
#pragma unroll
    for (int i = 0; i < 8; ++i) {
      const unsigned short h = f2bf_rne(fv[i]);
      ah[i] = (short)h;
      al[i] = (short)f2bf_rne(fv[i] - bfu2f(h));
    }
#pragma unroll
    for (int nt = 0; nt < 4; ++nt) {
      const int n = nt * 16 + lrow;
      int off = (n << 8) + (ks * 64 + lk * 16);
      off ^= (n & 7) << 4;
      const short8 bh = *(const short8*)((const char*)wt_hi + off);
      const short8 bl = *(const short8*)((const char*)wt_lo + off);
      acc[nt] = __builtin_amdgcn_mfma_f32_16x16x32_bf16(ah, bh, acc[nt], 0, 0, 0);
      acc[nt] = __builtin_amdgcn_mfma_f32_16x16x32_bf16(al, bh, acc[nt], 0, 0, 0);
      acc[nt] = __builtin_amdgcn_mfma_f32_16x16x32_bf16(ah, bl, acc[nt], 0, 0, 0);
    }
  }

  // C/D: col = lane&15, row = (lane>>4)*4 + reg  [HW-verified mapping]
#pragma unroll
  for (int nt = 0; nt < 4; ++nt) {
#pragma unroll
    for (int r = 0; r < 4; ++r) {
      const int row = m0 + lk * 4 + r;
      if (full || row < n_nodes)
        pre[(size_t)row * F_OUT + nt * 16 + lrow] = f2bf_rne(acc[nt][r]);
    }
  }
}

// ---------------------------------------------------------------------------
// Kernel 2: row_ptr[r] = lower_bound(edge_row, r)  (edge_row sorted)
// ---------------------------------------------------------------------------
__global__ __launch_bounds__(256) void gcn_rowptr(
    const int* __restrict__ edge_row, int* __restrict__ row_ptr,
    int n_nodes, int n_edges) {
  const int r = blockIdx.x * blockDim.x + threadIdx.x;
  if (r > n_nodes) return;
  int lo = 0, hi = n_edges;
  while (lo < hi) {
    const int mid = (lo + hi) >> 1;
    if (edge_row[mid] < r) lo = mid + 1; else hi = mid;
  }
  row_ptr[r] = lo;
}

// ---------------------------------------------------------------------------
// Kernel 3: out[r][f] = relu( sum_e val[e] * pre_bf16[col[e]][f] )
// One wave per row; row forced uniform via readfirstlane so ALL edge
// metadata loads become scalar (s_load) — zero LDS/bpermute traffic.
// 8 independent 128B gathers in flight; fixed sum order -> deterministic.
// ---------------------------------------------------------------------------
__global__ __launch_bounds__(256) void gcn_spmm(
    const unsigned short* __restrict__ pre, const int* __restrict__ row_ptr,
    const int* __restrict__ edge_col, const float* __restrict__ edge_val,
    float* __restrict__ out, int n_nodes) {
  const int lane = threadIdx.x & 63;
  int row = (int)((blockIdx.x * blockDim.x + threadIdx.x) >> 6);
  row = __builtin_amdgcn_readfirstlane(row);
  if (row >= n_nodes) return;
  const int e0 = row_ptr[row];
  const int e1 = row_ptr[row + 1];
  float a0 = 0.f, a1 = 0.f, a2 = 0.f, a3 = 0.f;
  int e = e0;
  for (; e + 8 <= e1; e += 8) {
    const int c0 = edge_col[e + 0], c1 = edge_col[e + 1];
    const int c2 = edge_col[e + 2], c3 = edge_col[e + 3];
    const int c4 = edge_col[e + 4], c5 = edge_col[e + 5];
    const int c6 = edge_col[e + 6], c7 = edge_col[e + 7];
    const float v0 = edge_val[e + 0], v1 = edge_val[e + 1];
    const float v2 = edge_val[e + 2], v3 = edge_val[e + 3];
    const float v4 = edge_val[e + 4], v5 = edge_val[e + 5];
    const float v6 = edge_val[e + 6], v7 = edge_val[e + 7];
    const float p0 = bfu2f(pre[(size_t)c0 * F_OUT + lane]);
    const float p1 = bfu2f(pre[(size_t)c1 * F_OUT + lane]);
    const float p2 = bfu2f(pre[(size_t)c2 * F_OUT + lane]);
    const float p3 = bfu2f(pre[(size_t)c3 * F_OUT + lane]);
    const float p4 = bfu2f(pre[(size_t)c4 * F_OUT + lane]);
    const float p5 = bfu2f(pre[(size_t)c5 * F_OUT + lane]);
    const float p6 = bfu2f(pre[(size_t)c6 * F_OUT + lane]);
    const float p7 = bfu2f(pre[(size_t)c7 * F_OUT + lane]);
    a0 = fmaf(v0, p0, a0); a1 = fmaf(v1, p1, a1);
    a2 = fmaf(v2, p2, a2); a3 = fmaf(v3, p3, a3);
    a0 = fmaf(v4, p4, a0); a1 = fmaf(v5, p5, a1);
    a2 = fmaf(v6, p6, a2); a3 = fmaf(v7, p7, a3);
  }
  for (; e < e1; ++e)
    a0 = fmaf(edge_val[e], bfu2f(pre[(size_t)edge_col[e] * F_OUT + lane]), a0);
  out[(size_t)row * F_OUT + lane] = fmaxf((a0 + a1) + (a2 + a3), 0.f);
}

extern "C" void kernel_launch(void* const* d_in, const int* in_sizes, int n_in,
                              void* d_out, int out_size, void* d_ws, size_t ws_size,
                              hipStream_t stream) {
  const float* x        = (const float*)d_in[0];
  const float* w        = (const float*)d_in[1];
  const int*   edge_row = (const int*)d_in[2];
  const int*   edge_col = (const int*)d_in[3];
  const float* edge_val = (const float*)d_in[4];
  float* out = (float*)d_out;

  const int n_nodes = in_sizes[0] / F_IN;   // 50000
  const int n_edges = in_sizes[2];          // 800000

  unsigned short* pre = (unsigned short*)d_ws;  // n_nodes*64 bf16 = 6.4 MB
  int* row_ptr = (int*)((char*)d_ws +
                        (size_t)n_nodes * F_OUT * sizeof(unsigned short));

  const int m_tiles = (n_nodes + 15) / 16;
  const int gemm_blocks = (m_tiles + 3) / 4;
  gcn_gemm<<<gemm_blocks, 256, 0, stream>>>(x, w, pre, n_nodes);

  const int rp_blocks = (n_nodes + 1 + 255) / 256;
  gcn_rowptr<<<rp_blocks, 256, 0, stream>>>(edge_row, row_ptr, n_nodes, n_edges);

  const int spmm_blocks = ((size_t)n_nodes * 64 + 255) / 256;
  gcn_spmm<<<spmm_blocks, 256, 0, stream>>>(pre, row_ptr, edge_col, edge_val,
                                            out, n_nodes);
}

// Round 4
// 32.653 us; speedup vs baseline: 3.4482x; 1.5490x over previous
//
#include <hip/hip_runtime.h>
#include <hip/hip_bf16.h>

#define F_IN 128
#define F_OUT 64

typedef __attribute__((ext_vector_type(8))) short short8;
typedef __attribute__((ext_vector_type(4))) float f32x4;

__device__ __forceinline__ unsigned short f2bf_rne(float f) {
  unsigned int u = __builtin_bit_cast(unsigned int, f);
  u += 0x7fffu + ((u >> 16) & 1u);
  return (unsigned short)(u >> 16);
}
__device__ __forceinline__ float bfu2f(unsigned short u) {
  return __builtin_bit_cast(float, (unsigned int)u << 16);
}

// ---------------------------------------------------------------------------
// Kernel A (fused): blocks [0, gemm_blocks) compute pre = bf16(x @ W) via
// MFMA; blocks [gemm_blocks, ..) compute row_ptr by binary search (hides
// under the GEMM, saves a launch).
//
// GEMM: wave -> 16-row m-tile. W^T staged bf16 (single-rounded) in 16 KB LDS,
// XOR-swizzled (^(n&7)<<4) -> 2-way-max conflicts on b128 frag reads.
// Staging reads w COALESCED (float4) and scatter-writes u16 (once/block).
// x kept fp32-accurate via hi/lo split: acc = ah*bh + al*bh (2 MFMA).
// ---------------------------------------------------------------------------
__global__ __launch_bounds__(256) void gcn_gemm_rowptr(
    const float* __restrict__ x, const float* __restrict__ w,
    unsigned short* __restrict__ pre,
    const int* __restrict__ edge_row, int* __restrict__ row_ptr,
    int n_nodes, int n_edges, int gemm_blocks) {
  const int tid = threadIdx.x;

  if (blockIdx.x >= gemm_blocks) {  // ---- rowptr path ----
    const int r = (blockIdx.x - gemm_blocks) * 256 + tid;
    if (r > n_nodes) return;
    int lo = 0, hi = n_edges;
    while (lo < hi) {
      const int mid = (lo + hi) >> 1;
      if (edge_row[mid] < r) lo = mid + 1; else hi = mid;
    }
    row_ptr[r] = lo;
    return;
  }

  // ---- GEMM path ----
  __shared__ __align__(16) unsigned short wt_hi[64 * 128];  // 16 KB

  {  // stage W^T: coalesced float4 reads, convert, scatter u16 into LDS
#pragma unroll
    for (int i = 0; i < 8; ++i) {
      const int flat4 = tid + i * 256;           // float4 index
      const float4 v = ((const float4*)w)[flat4];
      const float fv[4] = {v.x, v.y, v.z, v.w};
#pragma unroll
      for (int j = 0; j < 4; ++j) {
        const int flat = flat4 * 4 + j;          // flat = k*64 + n
        const int k = flat >> 6;
        const int n = flat & 63;
        int off = (n << 8) + (k << 1);
        off ^= (n & 7) << 4;
        *(unsigned short*)((char*)wt_hi + off) = f2bf_rne(fv[j]);
      }
    }
  }
  __syncthreads();

  const int lane = tid & 63;
  const int mt = blockIdx.x * 4 + (tid >> 6);
  const int m0 = mt * 16;
  if (m0 >= n_nodes) return;

  const int lrow = lane & 15;
  const int lk = lane >> 4;
  const bool full = (m0 + 16 <= n_nodes);
  const int arow = full ? (m0 + lrow) : min(m0 + lrow, n_nodes - 1);

  f32x4 acc[4];
#pragma unroll
  for (int i = 0; i < 4; ++i) acc[i] = (f32x4){0.f, 0.f, 0.f, 0.f};

#pragma unroll
  for (int ks = 0; ks < 4; ++ks) {
    const float4* xp =
        (const float4*)(x + (size_t)arow * F_IN + ks * 32 + lk * 8);
    const float4 q0 = xp[0];
    const float4 q1 = xp[1];
    const float fv[8] = {q0.x, q0.y, q0.z, q0.w, q1.x, q1.y, q1.z, q1.w};
    short8 ah, al;
#pragma unroll
    for (int i = 0; i < 8; ++i) {
      const unsigned short h = f2bf_rne(fv[i]);
      ah[i] = (short)h;
      al[i] = (short)f2bf_rne(fv[i] - bfu2f(h));
    }
#pragma unroll
    for (int nt = 0; nt < 4; ++nt) {
      const int n = nt * 16 + lrow;
      int off = (n << 8) + (ks * 64 + lk * 16);
      off ^= (n & 7) << 4;
      const short8 bh = *(const short8*)((const char*)wt_hi + off);
      acc[nt] = __builtin_amdgcn_mfma_f32_16x16x32_bf16(ah, bh, acc[nt], 0, 0, 0);
      acc[nt] = __builtin_amdgcn_mfma_f32_16x16x32_bf16(al, bh, acc[nt], 0, 0, 0);
    }
  }

  // C/D: col = lane&15, row = (lane>>4)*4 + reg  [HW-verified]
#pragma unroll
  for (int nt = 0; nt < 4; ++nt) {
#pragma unroll
    for (int r = 0; r < 4; ++r) {
      const int row = m0 + lk * 4 + r;
      if (full || row < n_nodes)
        pre[(size_t)row * F_OUT + nt * 16 + lrow] = f2bf_rne(acc[nt][r]);
    }
  }
}

// ---------------------------------------------------------------------------
// Kernel B: out[r][f] = relu( sum_e val[e] * pre_bf16[col[e]][f] )
// One wave per row, HALF-WAVE per edge: lanes 0-31 take edge j (feature pair
// fl = lane&31 -> uint = 2 bf16), lanes 32-63 take edge j+1. One load instr
// covers 2 edges (2 x 128B txns); unroll 8 -> 16 edges in flight. Parity
// partials merged with one shfl_xor(32); fixed order -> deterministic.
// ---------------------------------------------------------------------------
__global__ __launch_bounds__(256) void gcn_spmm(
    const unsigned short* __restrict__ pre, const int* __restrict__ row_ptr,
    const int* __restrict__ edge_col, const float* __restrict__ edge_val,
    float* __restrict__ out, int n_nodes) {
  const int lane = threadIdx.x & 63;
  const int half = lane >> 5;
  const int fl = lane & 31;
  int row = (int)((blockIdx.x * blockDim.x + threadIdx.x) >> 6);
  row = __builtin_amdgcn_readfirstlane(row);
  if (row >= n_nodes) return;
  const int e0 = row_ptr[row];
  const int e1 = row_ptr[row + 1];

  float a0 = 0.f, a1 = 0.f, a2 = 0.f, a3 = 0.f;

  for (int base = e0; base < e1; base += 64) {
    const int cnt = min(64, e1 - base);
    int myc = 0;
    float myv = 0.f;
    if (lane < cnt) {
      myc = edge_col[base + lane] << 6;  // element offset of the row
      myv = edge_val[base + lane];
    }
    const int nb = (cnt + 15) >> 4;  // 16 edges per iteration
    for (int b = 0; b < nb; ++b) {
      const int j0 = b * 16;
#pragma unroll
      for (int u = 0; u < 8; u += 2) {
        const int i0 = j0 + u * 2 + half;
        const int i1 = j0 + (u + 1) * 2 + half;
        const int c0 = __shfl(myc, i0);
        const float v0 = __shfl(myv, i0);
        const int c1 = __shfl(myc, i1);
        const float v1 = __shfl(myv, i1);
        const unsigned int p0 =
            *(const unsigned int*)((const char*)pre + ((size_t)c0 << 1) + (fl << 2));
        const unsigned int p1 =
            *(const unsigned int*)((const char*)pre + ((size_t)c1 << 1) + (fl << 2));
        a0 = fmaf(v0, bfu2f((unsigned short)(p0 & 0xffff)), a0);
        a1 = fmaf(v0, bfu2f((unsigned short)(p0 >> 16)), a1);
        a2 = fmaf(v1, bfu2f((unsigned short)(p1 & 0xffff)), a2);
        a3 = fmaf(v1, bfu2f((unsigned short)(p1 >> 16)), a3);
      }
    }
  }

  // merge edge-parity halves: lanes l and l^32 hold same feature pair
  float s0 = (a0 + a2) + __shfl_xor(a0 + a2, 32);
  float s1 = (a1 + a3) + __shfl_xor(a1 + a3, 32);
  if (half == 0) {
    float2 o = make_float2(fmaxf(s0, 0.f), fmaxf(s1, 0.f));
    *(float2*)(out + (size_t)row * F_OUT + fl * 2) = o;
  }
}

extern "C" void kernel_launch(void* const* d_in, const int* in_sizes, int n_in,
                              void* d_out, int out_size, void* d_ws, size_t ws_size,
                              hipStream_t stream) {
  const float* x        = (const float*)d_in[0];
  const float* w        = (const float*)d_in[1];
  const int*   edge_row = (const int*)d_in[2];
  const int*   edge_col = (const int*)d_in[3];
  const float* edge_val = (const float*)d_in[4];
  float* out = (float*)d_out;

  const int n_nodes = in_sizes[0] / F_IN;   // 50000
  const int n_edges = in_sizes[2];          // 800000

  unsigned short* pre = (unsigned short*)d_ws;  // n_nodes*64 bf16 = 6.4 MB
  int* row_ptr = (int*)((char*)d_ws +
                        (size_t)n_nodes * F_OUT * sizeof(unsigned short));

  const int m_tiles = (n_nodes + 15) / 16;
  const int gemm_blocks = (m_tiles + 3) / 4;
  const int rp_blocks = (n_nodes + 1 + 255) / 256;
  gcn_gemm_rowptr<<<gemm_blocks + rp_blocks, 256, 0, stream>>>(
      x, w, pre, edge_row, row_ptr, n_nodes, n_edges, gemm_blocks);

  const int spmm_blocks = ((size_t)n_nodes * 64 + 255) / 256;
  gcn_spmm<<<spmm_blocks, 256, 0, stream>>>(pre, row_ptr, edge_col, edge_val,
                                            out, n_nodes);
}